// Round 1
// baseline (89.217 us; speedup 1.0000x reference)
//
#include <hip/hip_runtime.h>
#include <math.h>

#define NV 8
#define NBINS 128
#define GRID 256
#define BLK 512
#define NWAVE (BLK / 64)

// Persistent device globals: partials + sense-reversing barrier state.
// Self-consistent across graph replays (cnt returns to 0, gen monotonically
// increments), no dependence on harness-poisoned d_ws.
__device__ float g_pmin[GRID][NV];
__device__ float g_pmax[GRID][NV];
__device__ unsigned g_cnt = 0;
__device__ unsigned g_gen = 0;

__global__ __launch_bounds__(BLK) void k_fused(const float* __restrict__ feats,
                                               float* __restrict__ out, int n) {
    const int tid = threadIdx.x;
    const int bid = blockIdx.x;
    const int gid = bid * BLK + tid;
    const int nth = GRID * BLK;
    const int wave = tid >> 6, lane = tid & 63;

    // ---------------- phase 1: grid-stride column min/max ----------------
    float lmin[NV], lmax[NV];
#pragma unroll
    for (int c = 0; c < NV; ++c) { lmin[c] = __builtin_inff(); lmax[c] = -__builtin_inff(); }
    const int n4 = n >> 2;
    const float4* f4 = (const float4*)feats;
    // stride (nth) is even in quads, so each thread's quad parity is fixed:
    // quad q covers columns (4q)&7 .. +3, i.e. cols 0-3 or 4-7.
    if (((gid << 2) & 7) == 0) {
        for (int q = gid; q < n4; q += nth) {
            float4 v = f4[q];
            lmin[0] = fminf(lmin[0], v.x); lmax[0] = fmaxf(lmax[0], v.x);
            lmin[1] = fminf(lmin[1], v.y); lmax[1] = fmaxf(lmax[1], v.y);
            lmin[2] = fminf(lmin[2], v.z); lmax[2] = fmaxf(lmax[2], v.z);
            lmin[3] = fminf(lmin[3], v.w); lmax[3] = fmaxf(lmax[3], v.w);
        }
    } else {
        for (int q = gid; q < n4; q += nth) {
            float4 v = f4[q];
            lmin[4] = fminf(lmin[4], v.x); lmax[4] = fmaxf(lmax[4], v.x);
            lmin[5] = fminf(lmin[5], v.y); lmax[5] = fmaxf(lmax[5], v.y);
            lmin[6] = fminf(lmin[6], v.z); lmax[6] = fmaxf(lmax[6], v.z);
            lmin[7] = fminf(lmin[7], v.w); lmax[7] = fmaxf(lmax[7], v.w);
        }
    }
    // generic tail (n % 4 != 0) — static-index via unrolled predicate
    for (int i = (n4 << 2) + gid; i < n; i += nth) {
        float v = feats[i];
        int c = i & 7;
#pragma unroll
        for (int cc = 0; cc < NV; ++cc)
            if (cc == c) { lmin[cc] = fminf(lmin[cc], v); lmax[cc] = fmaxf(lmax[cc], v); }
    }
    // 64-lane wave butterfly per column
#pragma unroll
    for (int c = 0; c < NV; ++c) {
        float mn = lmin[c], mx = lmax[c];
#pragma unroll
        for (int m = 32; m >= 1; m >>= 1) {
            mn = fminf(mn, __shfl_xor(mn, m));
            mx = fmaxf(mx, __shfl_xor(mx, m));
        }
        lmin[c] = mn; lmax[c] = mx;
    }
    __shared__ float smin[NWAVE][NV], smax[NWAVE][NV];
    if (lane == 0) {
#pragma unroll
        for (int c = 0; c < NV; ++c) { smin[wave][c] = lmin[c]; smax[wave][c] = lmax[c]; }
    }
    __syncthreads();
    if (tid < NV) {
        float mn = __builtin_inff(), mx = -__builtin_inff();
#pragma unroll
        for (int w = 0; w < NWAVE; ++w) {
            mn = fminf(mn, smin[w][tid]);
            mx = fmaxf(mx, smax[w][tid]);
        }
        // agent-scope stores: partials go to the coherence point, readable
        // cross-XCD after the barrier's acquire.
        __hip_atomic_store(&g_pmin[bid][tid], mn, __ATOMIC_RELAXED, __HIP_MEMORY_SCOPE_AGENT);
        __hip_atomic_store(&g_pmax[bid][tid], mx, __ATOMIC_RELAXED, __HIP_MEMORY_SCOPE_AGENT);
    }
    __syncthreads();   // partial stores issued before tid0's fence/arrival

    // ---------------- grid barrier (sense-reversing) ----------------
    // GRID=256 blocks, 1 block/CU on 256 CUs -> all blocks co-resident by
    // construction; bounded spin is a no-hang failsafe only.
    if (tid == 0) {
        __threadfence();  // device-scope release of this block's stores
        unsigned my = __hip_atomic_load(&g_gen, __ATOMIC_RELAXED, __HIP_MEMORY_SCOPE_AGENT);
        unsigned prev = __hip_atomic_fetch_add(&g_cnt, 1u, __ATOMIC_ACQ_REL, __HIP_MEMORY_SCOPE_AGENT);
        if (prev == GRID - 1) {
            __hip_atomic_store(&g_cnt, 0u, __ATOMIC_RELAXED, __HIP_MEMORY_SCOPE_AGENT);
            __hip_atomic_fetch_add(&g_gen, 1u, __ATOMIC_RELEASE, __HIP_MEMORY_SCOPE_AGENT);
        } else {
            int spins = 0;
            while (__hip_atomic_load(&g_gen, __ATOMIC_ACQUIRE, __HIP_MEMORY_SCOPE_AGENT) == my) {
                __builtin_amdgcn_s_sleep(2);
                if (++spins > (1 << 22)) break;  // failsafe: never hang the harness
            }
        }
        __threadfence();
    }
    __syncthreads();

    // ---------------- phase 2a: combine the GRID partials ----------------
    __shared__ float cmin[4][NV], cmax[4][NV];
    __shared__ float sgmin[NV], sgmax[NV];
    if (wave < 4) {
        const int pb = (wave << 6) | lane;  // 4 waves x 64 lanes = 256 partials
        float mn[NV], mx[NV];
#pragma unroll
        for (int c = 0; c < NV; ++c) {
            mn[c] = __hip_atomic_load(&g_pmin[pb][c], __ATOMIC_RELAXED, __HIP_MEMORY_SCOPE_AGENT);
            mx[c] = __hip_atomic_load(&g_pmax[pb][c], __ATOMIC_RELAXED, __HIP_MEMORY_SCOPE_AGENT);
        }
#pragma unroll
        for (int c = 0; c < NV; ++c) {
#pragma unroll
            for (int m = 32; m >= 1; m >>= 1) {
                mn[c] = fminf(mn[c], __shfl_xor(mn[c], m));
                mx[c] = fmaxf(mx[c], __shfl_xor(mx[c], m));
            }
        }
        if (lane == 0) {
#pragma unroll
            for (int c = 0; c < NV; ++c) { cmin[wave][c] = mn[c]; cmax[wave][c] = mx[c]; }
        }
    }
    __syncthreads();
    if (tid < NV) {
        sgmin[tid] = fminf(fminf(cmin[0][tid], cmin[1][tid]), fminf(cmin[2][tid], cmin[3][tid]));
        sgmax[tid] = fmaxf(fmaxf(cmax[0][tid], cmax[1][tid]), fmaxf(cmax[2][tid], cmax[3][tid]));
    }
    __syncthreads();

    // ---------------- phase 2b: lin table (exact reference arithmetic) ----------------
    __shared__ float slin[NV * 129];  // +1 pad: bank = (129v+b)%32 = (v+b)%32
    __shared__ float sfmin[NV], sstep[NV], srstep[NV];
    for (int e = tid; e < NV * NBINS; e += BLK) {
        int v = e >> 7;
        int b = e & 127;
        float fmn = sgmin[v];
        float range = __fsub_rn(sgmax[v], fmn);        // (fmax - fmin), f32
        float tb = __fdiv_rn((float)b, 127.0f);        // t[b] = b/127, f32
        slin[v * 129 + b] = __fadd_rn(fmn, __fmul_rn(range, tb));  // mul then add, no FMA
    }
    __syncthreads();
    if (tid < NV) {
        float s0 = slin[tid * 129 + 0];
        float s1 = slin[tid * 129 + 1];
        sfmin[tid] = s0;
        float st = __fsub_rn(s1, s0);
        sstep[tid] = st;
        srstep[tid] = __fdiv_rn(1.0f, st);  // candidate-only; fixups make bin exact
    }
    __syncthreads();

    // ---------------- phase 2c: quantize, grid-stride ----------------
    // stride (nth) % 8 == 0, so each thread's column is fixed -> hoist everything
    const int v = gid & 7;
    const float fmn = sfmin[v];
    const float step = sstep[v];
    const float rstep = srstep[v];
    const float* lv = &slin[v * 129];
    for (int i = gid; i < n; i += nth) {
        const float feat = feats[i];
        // candidate, then exact monotone fix-up (cond evals ~2-3 typical)
        int b = (int)floorf(__fmul_rn(__fsub_rn(feat, fmn), rstep));
        b = b < 0 ? 0 : (b > 127 ? 127 : b);
        while (b < NBINS - 1 &&
               rintf(__fmul_rn(__fsub_rn(lv[b + 1], feat), 1.0e6f)) <= 0.0f) ++b;
        while (b > 0 &&
               rintf(__fmul_rn(__fsub_rn(lv[b], feat), 1.0e6f)) > 0.0f) --b;
        const float val = lv[b];
        const float reg = __fdiv_rn(fmaxf(__fsub_rn(feat, val), 0.0f), step);
        out[i] = (float)b;   // bins output, written as float
        out[n + i] = reg;    // regs output
    }
}

extern "C" void kernel_launch(void* const* d_in, const int* in_sizes, int n_in,
                              void* d_out, int out_size, void* d_ws, size_t ws_size,
                              hipStream_t stream) {
    const float* feats = (const float*)d_in[0];
    float* out = (float*)d_out;
    const int n = in_sizes[0];  // 100000 * 8 flat
    (void)d_ws; (void)ws_size;
    k_fused<<<GRID, BLK, 0, stream>>>(feats, out, n);
}

// Round 2
// 67.177 us; speedup vs baseline: 1.3281x; 1.3281x over previous
//
#include <hip/hip_runtime.h>
#include <math.h>

#define NV 8
#define NBINS 128
#define GRID_A 64
#define GRID_Q 1024
#define BLK_Q 256

// ws layout (floats):
// [0, 512)      pmin[GRID_A][8]
// [512, 1024)   pmax[GRID_A][8]

__global__ __launch_bounds__(256) void k_colminmax(const float* __restrict__ feats,
                                                   float* __restrict__ ws, int n) {
    const int tid = threadIdx.x;
    const int gt = blockIdx.x * blockDim.x + tid;
    const int nth = blockDim.x * gridDim.x;
    float lmin[NV], lmax[NV];
#pragma unroll
    for (int c = 0; c < NV; ++c) { lmin[c] = __builtin_inff(); lmax[c] = -__builtin_inff(); }
    const int n4 = n >> 2;
    const float4* f4 = (const float4*)feats;
    // stride (nth) is even in quads, so each thread's quad parity is fixed:
    // quad q covers columns (4q)&7 .. +3, i.e. cols 0-3 or 4-7.
    if (((gt << 2) & 7) == 0) {
        for (int q = gt; q < n4; q += nth) {
            float4 v = f4[q];
            lmin[0] = fminf(lmin[0], v.x); lmax[0] = fmaxf(lmax[0], v.x);
            lmin[1] = fminf(lmin[1], v.y); lmax[1] = fmaxf(lmax[1], v.y);
            lmin[2] = fminf(lmin[2], v.z); lmax[2] = fmaxf(lmax[2], v.z);
            lmin[3] = fminf(lmin[3], v.w); lmax[3] = fmaxf(lmax[3], v.w);
        }
    } else {
        for (int q = gt; q < n4; q += nth) {
            float4 v = f4[q];
            lmin[4] = fminf(lmin[4], v.x); lmax[4] = fmaxf(lmax[4], v.x);
            lmin[5] = fminf(lmin[5], v.y); lmax[5] = fmaxf(lmax[5], v.y);
            lmin[6] = fminf(lmin[6], v.z); lmax[6] = fmaxf(lmax[6], v.z);
            lmin[7] = fminf(lmin[7], v.w); lmax[7] = fmaxf(lmax[7], v.w);
        }
    }
    // generic tail (n % 4 != 0) — static-index via unrolled predicate
    for (int i = (n4 << 2) + gt; i < n; i += nth) {
        float v = feats[i];
        int c = i & 7;
#pragma unroll
        for (int cc = 0; cc < NV; ++cc)
            if (cc == c) { lmin[cc] = fminf(lmin[cc], v); lmax[cc] = fmaxf(lmax[cc], v); }
    }
    // 64-lane wave butterfly per column
#pragma unroll
    for (int c = 0; c < NV; ++c) {
        float mn = lmin[c], mx = lmax[c];
#pragma unroll
        for (int m = 32; m >= 1; m >>= 1) {
            mn = fminf(mn, __shfl_xor(mn, m));
            mx = fmaxf(mx, __shfl_xor(mx, m));
        }
        lmin[c] = mn; lmax[c] = mx;
    }
    __shared__ float smin[4][NV], smax[4][NV];
    const int wave = tid >> 6, lane = tid & 63;
    if (lane == 0) {
#pragma unroll
        for (int c = 0; c < NV; ++c) { smin[wave][c] = lmin[c]; smax[wave][c] = lmax[c]; }
    }
    __syncthreads();
    if (tid < NV) {
        float mn = fminf(fminf(smin[0][tid], smin[1][tid]), fminf(smin[2][tid], smin[3][tid]));
        float mx = fmaxf(fmaxf(smax[0][tid], smax[1][tid]), fmaxf(smax[2][tid], smax[3][tid]));
        ws[blockIdx.x * NV + tid] = mn;
        ws[GRID_A * NV + blockIdx.x * NV + tid] = mx;
    }
}

// Fused combine + lin build + quantize. Every block redundantly reduces the
// 64 partials (2 KB, one wave, LLC-served) — deletes the separate 64-thread
// k_combine dispatch and its launch gap.
__global__ __launch_bounds__(BLK_Q) void k_quantize2(const float* __restrict__ feats,
                                                     const float* __restrict__ ws,
                                                     float* __restrict__ out, int n) {
    __shared__ float sgmin[NV], sgmax[NV];
    __shared__ float slin[NV * 129];  // +1 pad: bank = (129v+b)%32 = (v+b)%32
    __shared__ float sfmin[NV], sstep[NV], srstep[NV];
    const int tid = threadIdx.x;

    // wave 0: combine the 64 partial blocks (lane l <-> partial l)
    if (tid < 64) {
        const float4* w4 = (const float4*)ws;
        float4 a  = w4[2 * tid];
        float4 b4 = w4[2 * tid + 1];
        float4 c4 = w4[2 * GRID_A + 2 * tid];
        float4 d4 = w4[2 * GRID_A + 2 * tid + 1];
        float mn[NV] = {a.x, a.y, a.z, a.w, b4.x, b4.y, b4.z, b4.w};
        float mx[NV] = {c4.x, c4.y, c4.z, c4.w, d4.x, d4.y, d4.z, d4.w};
#pragma unroll
        for (int c = 0; c < NV; ++c) {
#pragma unroll
            for (int m = 32; m >= 1; m >>= 1) {
                mn[c] = fminf(mn[c], __shfl_xor(mn[c], m));
                mx[c] = fmaxf(mx[c], __shfl_xor(mx[c], m));
            }
        }
        if (tid == 0) {
#pragma unroll
            for (int c = 0; c < NV; ++c) { sgmin[c] = mn[c]; sgmax[c] = mx[c]; }
        }
    }
    __syncthreads();

    // lin table (exact reference arithmetic: mul then add, no FMA)
    for (int e = tid; e < NV * NBINS; e += BLK_Q) {
        int v = e >> 7;
        int b = e & 127;
        float fmn = sgmin[v];
        float range = __fsub_rn(sgmax[v], fmn);        // (fmax - fmin), f32
        float tb = __fdiv_rn((float)b, 127.0f);        // t[b] = b/127, f32
        slin[v * 129 + b] = __fadd_rn(fmn, __fmul_rn(range, tb));
    }
    __syncthreads();
    if (tid < NV) {
        float s0 = slin[tid * 129 + 0];
        float s1 = slin[tid * 129 + 1];
        sfmin[tid] = s0;
        float st = __fsub_rn(s1, s0);
        sstep[tid] = st;
        srstep[tid] = __fdiv_rn(1.0f, st);  // candidate-only; fixups make bin exact
    }
    __syncthreads();

    // quantize, grid-stride; stride % 8 == 0 so each thread's column is fixed
    const int gid = blockIdx.x * BLK_Q + tid;
    const int nth = GRID_Q * BLK_Q;
    const int v = gid & 7;
    const float fmn = sfmin[v];
    const float step = sstep[v];
    const float rstep = srstep[v];
    const float* lv = &slin[v * 129];
    for (int i = gid; i < n; i += nth) {
        const float feat = feats[i];
        // candidate, then exact monotone fix-up (cond evals ~2-3 typical)
        int b = (int)floorf(__fmul_rn(__fsub_rn(feat, fmn), rstep));
        b = b < 0 ? 0 : (b > 127 ? 127 : b);
        while (b < NBINS - 1 &&
               rintf(__fmul_rn(__fsub_rn(lv[b + 1], feat), 1.0e6f)) <= 0.0f) ++b;
        while (b > 0 &&
               rintf(__fmul_rn(__fsub_rn(lv[b], feat), 1.0e6f)) > 0.0f) --b;
        const float val = lv[b];
        const float reg = __fdiv_rn(fmaxf(__fsub_rn(feat, val), 0.0f), step);
        out[i] = (float)b;   // bins output, written as float
        out[n + i] = reg;    // regs output
    }
}

extern "C" void kernel_launch(void* const* d_in, const int* in_sizes, int n_in,
                              void* d_out, int out_size, void* d_ws, size_t ws_size,
                              hipStream_t stream) {
    const float* feats = (const float*)d_in[0];
    float* ws = (float*)d_ws;
    float* out = (float*)d_out;
    const int n = in_sizes[0];  // 100000 * 8 flat
    k_colminmax<<<GRID_A, 256, 0, stream>>>(feats, ws, n);
    k_quantize2<<<GRID_Q, BLK_Q, 0, stream>>>(feats, ws, out, n);
}

// Round 3
// 65.374 us; speedup vs baseline: 1.3647x; 1.0276x over previous
//
#include <hip/hip_runtime.h>
#include <math.h>

#define NV 8
#define NBINS 128
#define GRID_A 64
#define GRID_Q 400
#define BLK_Q 256

// ws layout (floats):
// [0, 512)      pmin[GRID_A][8]
// [512, 1024)   pmax[GRID_A][8]

__global__ __launch_bounds__(256) void k_colminmax(const float* __restrict__ feats,
                                                   float* __restrict__ ws, int n) {
    const int tid = threadIdx.x;
    const int gt = blockIdx.x * blockDim.x + tid;
    const int nth = blockDim.x * gridDim.x;
    float lmin[NV], lmax[NV];
#pragma unroll
    for (int c = 0; c < NV; ++c) { lmin[c] = __builtin_inff(); lmax[c] = -__builtin_inff(); }
    const int n4 = n >> 2;
    const float4* f4 = (const float4*)feats;
    // stride (nth) is even in quads, so each thread's quad parity is fixed:
    // quad q covers columns (4q)&7 .. +3, i.e. cols 0-3 or 4-7.
    // Unroll-by-4: 4 independent float4 loads in flight per iteration
    // (latency-bound fix: feats is HBM-cold after the 256MiB ws poison fill).
    int q = gt;
    if (((gt << 2) & 7) == 0) {
        for (; q + 3 * nth < n4; q += 4 * nth) {
            float4 a = f4[q];
            float4 b = f4[q + nth];
            float4 c = f4[q + 2 * nth];
            float4 d = f4[q + 3 * nth];
            lmin[0] = fminf(fminf(lmin[0], fminf(a.x, b.x)), fminf(c.x, d.x));
            lmax[0] = fmaxf(fmaxf(lmax[0], fmaxf(a.x, b.x)), fmaxf(c.x, d.x));
            lmin[1] = fminf(fminf(lmin[1], fminf(a.y, b.y)), fminf(c.y, d.y));
            lmax[1] = fmaxf(fmaxf(lmax[1], fmaxf(a.y, b.y)), fmaxf(c.y, d.y));
            lmin[2] = fminf(fminf(lmin[2], fminf(a.z, b.z)), fminf(c.z, d.z));
            lmax[2] = fmaxf(fmaxf(lmax[2], fmaxf(a.z, b.z)), fmaxf(c.z, d.z));
            lmin[3] = fminf(fminf(lmin[3], fminf(a.w, b.w)), fminf(c.w, d.w));
            lmax[3] = fmaxf(fmaxf(lmax[3], fmaxf(a.w, b.w)), fmaxf(c.w, d.w));
        }
        for (; q < n4; q += nth) {
            float4 v = f4[q];
            lmin[0] = fminf(lmin[0], v.x); lmax[0] = fmaxf(lmax[0], v.x);
            lmin[1] = fminf(lmin[1], v.y); lmax[1] = fmaxf(lmax[1], v.y);
            lmin[2] = fminf(lmin[2], v.z); lmax[2] = fmaxf(lmax[2], v.z);
            lmin[3] = fminf(lmin[3], v.w); lmax[3] = fmaxf(lmax[3], v.w);
        }
    } else {
        for (; q + 3 * nth < n4; q += 4 * nth) {
            float4 a = f4[q];
            float4 b = f4[q + nth];
            float4 c = f4[q + 2 * nth];
            float4 d = f4[q + 3 * nth];
            lmin[4] = fminf(fminf(lmin[4], fminf(a.x, b.x)), fminf(c.x, d.x));
            lmax[4] = fmaxf(fmaxf(lmax[4], fmaxf(a.x, b.x)), fmaxf(c.x, d.x));
            lmin[5] = fminf(fminf(lmin[5], fminf(a.y, b.y)), fminf(c.y, d.y));
            lmax[5] = fmaxf(fmaxf(lmax[5], fmaxf(a.y, b.y)), fmaxf(c.y, d.y));
            lmin[6] = fminf(fminf(lmin[6], fminf(a.z, b.z)), fminf(c.z, d.z));
            lmax[6] = fmaxf(fmaxf(lmax[6], fmaxf(a.z, b.z)), fmaxf(c.z, d.z));
            lmin[7] = fminf(fminf(lmin[7], fminf(a.w, b.w)), fminf(c.w, d.w));
            lmax[7] = fmaxf(fmaxf(lmax[7], fmaxf(a.w, b.w)), fmaxf(c.w, d.w));
        }
        for (; q < n4; q += nth) {
            float4 v = f4[q];
            lmin[4] = fminf(lmin[4], v.x); lmax[4] = fmaxf(lmax[4], v.x);
            lmin[5] = fminf(lmin[5], v.y); lmax[5] = fmaxf(lmax[5], v.y);
            lmin[6] = fminf(lmin[6], v.z); lmax[6] = fmaxf(lmax[6], v.z);
            lmin[7] = fminf(lmin[7], v.w); lmax[7] = fmaxf(lmax[7], v.w);
        }
    }
    // generic tail (n % 4 != 0) — static-index via unrolled predicate
    for (int i = (n4 << 2) + gt; i < n; i += nth) {
        float v = feats[i];
        int c = i & 7;
#pragma unroll
        for (int cc = 0; cc < NV; ++cc)
            if (cc == c) { lmin[cc] = fminf(lmin[cc], v); lmax[cc] = fmaxf(lmax[cc], v); }
    }
    // 64-lane wave butterfly per column
#pragma unroll
    for (int c = 0; c < NV; ++c) {
        float mn = lmin[c], mx = lmax[c];
#pragma unroll
        for (int m = 32; m >= 1; m >>= 1) {
            mn = fminf(mn, __shfl_xor(mn, m));
            mx = fmaxf(mx, __shfl_xor(mx, m));
        }
        lmin[c] = mn; lmax[c] = mx;
    }
    __shared__ float smin[4][NV], smax[4][NV];
    const int wave = tid >> 6, lane = tid & 63;
    if (lane == 0) {
#pragma unroll
        for (int c = 0; c < NV; ++c) { smin[wave][c] = lmin[c]; smax[wave][c] = lmax[c]; }
    }
    __syncthreads();
    if (tid < NV) {
        float mn = fminf(fminf(smin[0][tid], smin[1][tid]), fminf(smin[2][tid], smin[3][tid]));
        float mx = fmaxf(fmaxf(smax[0][tid], smax[1][tid]), fmaxf(smax[2][tid], smax[3][tid]));
        ws[blockIdx.x * NV + tid] = mn;
        ws[GRID_A * NV + blockIdx.x * NV + tid] = mx;
    }
}

// Per-quad processing: 4 consecutive elements = 4 consecutive columns
// (quad parity fixed by q&1). Exact reference bin rule preserved.
__device__ __forceinline__ void proc4(float4 fv, int q, const float* __restrict__ slin,
                                      const float* __restrict__ sfmin,
                                      const float* __restrict__ sstep,
                                      const float* __restrict__ srstep,
                                      float* __restrict__ out, int n) {
    const int v0 = (q << 2) & 7;  // 0 or 4
    const int i0 = q << 2;
    float fe[4] = {fv.x, fv.y, fv.z, fv.w};
    float bins[4], regs[4];
#pragma unroll
    for (int j = 0; j < 4; ++j) {
        const int v = v0 + j;
        const float* lv = &slin[v * 129];
        const float feat = fe[j];
        const float fmn = sfmin[v];
        const float step = sstep[v];
        const float rstep = srstep[v];
        // candidate, then exact monotone fix-up (cond evals ~2-3 typical)
        int b = (int)floorf(__fmul_rn(__fsub_rn(feat, fmn), rstep));
        b = b < 0 ? 0 : (b > 127 ? 127 : b);
        while (b < NBINS - 1 &&
               rintf(__fmul_rn(__fsub_rn(lv[b + 1], feat), 1.0e6f)) <= 0.0f) ++b;
        while (b > 0 &&
               rintf(__fmul_rn(__fsub_rn(lv[b], feat), 1.0e6f)) > 0.0f) --b;
        const float val = lv[b];
        bins[j] = (float)b;
        regs[j] = __fdiv_rn(fmaxf(__fsub_rn(feat, val), 0.0f), step);
    }
    *(float4*)(out + i0) = make_float4(bins[0], bins[1], bins[2], bins[3]);
    if ((n & 3) == 0) {  // out+n is 16B-aligned iff n%4==0
        *(float4*)(out + n + i0) = make_float4(regs[0], regs[1], regs[2], regs[3]);
    } else {
        out[n + i0 + 0] = regs[0]; out[n + i0 + 1] = regs[1];
        out[n + i0 + 2] = regs[2]; out[n + i0 + 3] = regs[3];
    }
}

// Fused combine + lin build + quantize. feats loads are issued BEFORE the
// combine/lin preamble so HBM latency hides under it; all I/O is float4.
__global__ __launch_bounds__(BLK_Q) void k_quantize2(const float* __restrict__ feats,
                                                     const float* __restrict__ ws,
                                                     float* __restrict__ out, int n) {
    __shared__ float sgmin[NV], sgmax[NV];
    __shared__ float slin[NV * 129];  // +1 pad: bank = (129v+b)%32 = (v+b)%32
    __shared__ float sfmin[NV], sstep[NV], srstep[NV];
    const int tid = threadIdx.x;
    const int gid = blockIdx.x * BLK_Q + tid;
    const int nth = GRID_Q * BLK_Q;
    const int n4 = n >> 2;
    const float4* f4 = (const float4*)feats;

    // ---- prefetch: issue this thread's feats quads NOW (up to 2 covers n) ----
    const int q0 = gid, q1 = gid + nth;
    float4 fv0, fv1;
    const bool h0 = q0 < n4, h1 = q1 < n4;
    if (h0) fv0 = f4[q0];
    if (h1) fv1 = f4[q1];

    // ---- wave 0: combine the 64 partial blocks (lane l <-> partial l) ----
    if (tid < 64) {
        const float4* w4 = (const float4*)ws;
        float4 a  = w4[2 * tid];
        float4 b4 = w4[2 * tid + 1];
        float4 c4 = w4[2 * GRID_A + 2 * tid];
        float4 d4 = w4[2 * GRID_A + 2 * tid + 1];
        float mn[NV] = {a.x, a.y, a.z, a.w, b4.x, b4.y, b4.z, b4.w};
        float mx[NV] = {c4.x, c4.y, c4.z, c4.w, d4.x, d4.y, d4.z, d4.w};
#pragma unroll
        for (int c = 0; c < NV; ++c) {
#pragma unroll
            for (int m = 32; m >= 1; m >>= 1) {
                mn[c] = fminf(mn[c], __shfl_xor(mn[c], m));
                mx[c] = fmaxf(mx[c], __shfl_xor(mx[c], m));
            }
        }
        if (tid == 0) {
#pragma unroll
            for (int c = 0; c < NV; ++c) { sgmin[c] = mn[c]; sgmax[c] = mx[c]; }
        }
    }
    __syncthreads();

    // ---- lin table (exact reference arithmetic: mul then add, no FMA) ----
    for (int e = tid; e < NV * NBINS; e += BLK_Q) {
        int v = e >> 7;
        int b = e & 127;
        float fmn = sgmin[v];
        float range = __fsub_rn(sgmax[v], fmn);        // (fmax - fmin), f32
        float tb = __fdiv_rn((float)b, 127.0f);        // t[b] = b/127, f32
        slin[v * 129 + b] = __fadd_rn(fmn, __fmul_rn(range, tb));
    }
    __syncthreads();
    if (tid < NV) {
        float s0 = slin[tid * 129 + 0];
        float s1 = slin[tid * 129 + 1];
        sfmin[tid] = s0;
        float st = __fsub_rn(s1, s0);
        sstep[tid] = st;
        srstep[tid] = __fdiv_rn(1.0f, st);  // candidate-only; fixups make bin exact
    }
    __syncthreads();

    // ---- quantize: prefetched quads, then (normally empty) safety strides ----
    if (h0) proc4(fv0, q0, slin, sfmin, sstep, srstep, out, n);
    if (h1) proc4(fv1, q1, slin, sfmin, sstep, srstep, out, n);
    for (int q = gid + 2 * nth; q < n4; q += nth)
        proc4(f4[q], q, slin, sfmin, sstep, srstep, out, n);

    // scalar tail (n % 4 != 0)
    for (int i = (n4 << 2) + gid; i < n; i += nth) {
        const int v = i & 7;
        const float feat = feats[i];
        const float* lv = &slin[v * 129];
        const float fmn = sfmin[v];
        const float step = sstep[v];
        int b = (int)floorf(__fmul_rn(__fsub_rn(feat, fmn), srstep[v]));
        b = b < 0 ? 0 : (b > 127 ? 127 : b);
        while (b < NBINS - 1 &&
               rintf(__fmul_rn(__fsub_rn(lv[b + 1], feat), 1.0e6f)) <= 0.0f) ++b;
        while (b > 0 &&
               rintf(__fmul_rn(__fsub_rn(lv[b], feat), 1.0e6f)) > 0.0f) --b;
        out[i] = (float)b;
        out[n + i] = __fdiv_rn(fmaxf(__fsub_rn(feat, lv[b]), 0.0f), step);
    }
}

extern "C" void kernel_launch(void* const* d_in, const int* in_sizes, int n_in,
                              void* d_out, int out_size, void* d_ws, size_t ws_size,
                              hipStream_t stream) {
    const float* feats = (const float*)d_in[0];
    float* ws = (float*)d_ws;
    float* out = (float*)d_out;
    const int n = in_sizes[0];  // 100000 * 8 flat
    k_colminmax<<<GRID_A, 256, 0, stream>>>(feats, ws, n);
    k_quantize2<<<GRID_Q, BLK_Q, 0, stream>>>(feats, ws, out, n);
}